// Round 7
// baseline (184.297 us; speedup 1.0000x reference)
//
#include <hip/hip_runtime.h>
#include <stdint.h>

// SpatialHyperedgeMP: out = ((inc + head) @ cur) / rowsum(inc + head)
//   head_ij = (inc_ij > 0) / sqrt(cnt_i),  cnt_i = #positives in row i
// Decomposition (single fused pass over inc):
//   out[i] = (inc@cur + invs_i * (mask@cur)) * rdeg_i
//   invs_i = 1/sqrt(cnt_i),  rdeg_i = 1/(s1_i + sqrt(cnt_i))
//   s1 (fp64) and cnt (int) accumulated during A staging -> exact denominator.
//
// R7: DS-pipe diet. R6 post-mortem: DS pipe was at ~77% (B LDS-write + B frag
// ds_reads dominate). B fragments are now read DIRECTLY from ws into registers
// (ws chunks are already in per-lane MFMA fragment layout) - no B LDS at all.
// LDS holds only A+M (4KB each, double-buffered) = 16.6 KB/block.
// BM=32 BN=256, 4 waves (wave tile 32x64), grid 512 -> 2 blocks/CU.
// Block swizzle keys nt to XCD half so each 4MB B-chunk stays L2-resident.
//
// ws usage: 8MB B chunks only.

#define NROWS 8192
#define DDIM  512

typedef float f32x4 __attribute__((ext_vector_type(4)));
typedef short s16x8 __attribute__((ext_vector_type(8)));

__device__ __forceinline__ unsigned short f2bf(float f) {
  union { float f; unsigned int u; } c; c.f = f;
  unsigned int u = c.u;
  unsigned int r = u + 0x7FFFu + ((u >> 16) & 1u);
  return (unsigned short)(r >> 16);
}

// ---------------- kernel 1: B prep (cur -> bf16 chunked-transposed) ----------------
// chunk layout: nt(2) x kt(128): 32KB chunk = [kg=8][nn=256][e=8] bf16
__global__ __launch_bounds__(256) void bprep_kernel(const float* __restrict__ cur,
                                                    unsigned char* __restrict__ bws) {
  int idx = blockIdx.x * 256 + threadIdx.x;  // 0..524287
  int n = idx & 511;
  int kg9 = idx >> 9;  // 0..1023
  int kt = kg9 >> 3;
  int kg = kg9 & 7;
  int k0 = kt * 64 + kg * 8;
  union { unsigned short h[8]; uint4 q; } u;
#pragma unroll
  for (int e = 0; e < 8; ++e)
    u.h[e] = f2bf(cur[(size_t)(k0 + e) * DDIM + n]);
  int nt = n >> 8, nn = n & 255;
  size_t off = ((size_t)(nt * 128 + kt) << 15) + ((size_t)kg << 12) + ((size_t)nn << 4);
  *(uint4*)(bws + off) = u.q;
}

// ---------------- kernel 2: fused stats + dual-GEMM ----------------
// BM=32 BN=256 BK=64, 256 threads = 4 waves (1M x 4N), wave tile 32x64.
// LDS (16.6KB): A0,A1,M0,M1 = 4KB each ([kg=8][slot=32][e=8] bf16, slot=row^kg).
// B frags: registers, loaded 1 tile ahead from ws. A regs: 2 tiles ahead.
// Only manual wait: lgkmcnt(0) before the per-tile barrier (A/M ds_writes).

#define FENCE() __builtin_amdgcn_sched_barrier(0)
#define BARRIER() __builtin_amdgcn_s_barrier()
#define WAITLGKM() asm volatile("s_waitcnt lgkmcnt(0)" ::: "memory")

__global__ __launch_bounds__(256, 2) void gemm_kernel(const float* __restrict__ inc,
                                                      const unsigned char* __restrict__ bws,
                                                      float* __restrict__ out) {
  __shared__ __align__(16) unsigned char smem[16640];
  unsigned char* const aBuf0 = smem;
  unsigned char* const aBuf1 = smem + 4096;
  unsigned char* const mBuf0 = smem + 8192;
  unsigned char* const mBuf1 = smem + 12288;

  const int tid = threadIdx.x;
  const int lane = tid & 63;
  const int wv = tid >> 6;        // 0..3
  // swizzle: ids 0..3 -> nt=0 (XCDs 0-3), ids 4..7 -> nt=1 (XCDs 4-7), assuming
  // round-robin id%8 -> XCD. Each XCD half then streams ONE 4MB B-chunk (L2-fit).
  const int id = blockIdx.x;      // 0..511
  const int nt = (id >> 2) & 1;
  const int mt = (id >> 3) * 4 + (id & 3);   // bijective 0..255
  const int brow = mt * 32;
  const int bcol = nt * 256;

  // A ownership: thread -> (row sm, k-octet sp); per tile: 2 float4 loads,
  // one b128 A-write + one b128 M-write.
  const int sm = tid >> 3;   // 0..31
  const int sp = tid & 7;    // 0..7  (k = sp*8 .. sp*8+7)
  const float4* gAr = (const float4*)(inc + (size_t)(brow + sm) * NROWS) + sp * 2;
  const int aWr = (sp << 9) + ((sm ^ sp) << 4);  // XOR swizzle

  const unsigned char* gBb = bws + ((size_t)(nt * 128) << 15);

  // fragment offsets
  int aOff[2][2];   // LDS byte offsets for A/M frags
  int bOff[8];      // ws byte offsets (within a 32KB kt-chunk) for B frags
#pragma unroll
  for (int kh = 0; kh < 2; ++kh) {
    int kg = kh * 4 + (lane >> 4);
#pragma unroll
    for (int g = 0; g < 2; ++g) {
      int r = g * 16 + (lane & 15);
      aOff[kh][g] = (kg << 9) + ((r ^ kg) << 4);
    }
#pragma unroll
    for (int cg = 0; cg < 4; ++cg)
      bOff[kh * 4 + cg] = (kg << 12) + ((wv * 64 + cg * 16 + (lane & 15)) << 4);
  }

  f32x4 acc1[2][4], acc2[2][4];
#pragma unroll
  for (int a = 0; a < 2; ++a)
#pragma unroll
    for (int b = 0; b < 4; ++b) {
      acc1[a][b] = (f32x4){0.f, 0.f, 0.f, 0.f};
      acc2[a][b] = (f32x4){0.f, 0.f, 0.f, 0.f};
    }

  double s1d = 0.0;
  int cnt = 0;
  float4 x0, x1, y0, y1;
  s16x8 bA[8], bB[8];   // B frag double reg-buffer (all indices static after unroll)

#define ISSUE_A(d0, d1, KT) do { d0 = gAr[(KT) * 16]; d1 = gAr[(KT) * 16 + 1]; } while (0)

#define LOADB(BS, KT) do {                                                                \
    const unsigned char* _g = gBb + ((size_t)(KT) << 15);                                 \
    _Pragma("unroll")                                                                     \
    for (int _i = 0; _i < 8; ++_i) BS[_i] = *(const s16x8*)(_g + bOff[_i]);               \
  } while (0)

// stage A tile: exact stats, RNE bf16 via v_cvt_pk, mask bf16 (1.0/0.0) -> LDS.
#define XFORM(s0, s1, ADST, MDST) do {                                                    \
    s1d += (double)s0.x + (double)s0.y + (double)s0.z + (double)s0.w;                     \
    s1d += (double)s1.x + (double)s1.y + (double)s1.z + (double)s1.w;                     \
    cnt += (s0.x > 0.f) + (s0.y > 0.f) + (s0.z > 0.f) + (s0.w > 0.f);                     \
    cnt += (s1.x > 0.f) + (s1.y > 0.f) + (s1.z > 0.f) + (s1.w > 0.f);                     \
    uint4 _a, _m;                                                                         \
    asm("v_cvt_pk_bf16_f32 %0, %1, %2" : "=v"(_a.x) : "v"(s0.x), "v"(s0.y));              \
    asm("v_cvt_pk_bf16_f32 %0, %1, %2" : "=v"(_a.y) : "v"(s0.z), "v"(s0.w));              \
    asm("v_cvt_pk_bf16_f32 %0, %1, %2" : "=v"(_a.z) : "v"(s1.x), "v"(s1.y));              \
    asm("v_cvt_pk_bf16_f32 %0, %1, %2" : "=v"(_a.w) : "v"(s1.z), "v"(s1.w));              \
    _m.x = (s0.x > 0.f ? 0x3F80u : 0u) | (s0.y > 0.f ? 0x3F800000u : 0u);                 \
    _m.y = (s0.z > 0.f ? 0x3F80u : 0u) | (s0.w > 0.f ? 0x3F800000u : 0u);                 \
    _m.z = (s1.x > 0.f ? 0x3F80u : 0u) | (s1.y > 0.f ? 0x3F800000u : 0u);                 \
    _m.w = (s1.z > 0.f ? 0x3F80u : 0u) | (s1.w > 0.f ? 0x3F800000u : 0u);                 \
    *(uint4*)((ADST) + aWr) = _a;                                                         \
    *(uint4*)((MDST) + aWr) = _m;                                                         \
  } while (0)

#define MFMA_TILE(AC, MC, BS) do {                                                        \
    __builtin_amdgcn_s_setprio(1);                                                        \
    _Pragma("unroll")                                                                     \
    for (int kh = 0; kh < 2; ++kh) {                                                      \
      s16x8 af[2], am[2];                                                                 \
      _Pragma("unroll")                                                                   \
      for (int g = 0; g < 2; ++g) af[g] = *(const s16x8*)((AC) + aOff[kh][g]);            \
      _Pragma("unroll")                                                                   \
      for (int g = 0; g < 2; ++g) am[g] = *(const s16x8*)((MC) + aOff[kh][g]);            \
      _Pragma("unroll")                                                                   \
      for (int rg = 0; rg < 2; ++rg)                                                      \
        _Pragma("unroll")                                                                 \
        for (int cg = 0; cg < 4; ++cg) {                                                  \
          acc1[rg][cg] = __builtin_amdgcn_mfma_f32_16x16x32_bf16(af[rg], BS[kh * 4 + cg], \
                                                                 acc1[rg][cg], 0, 0, 0); \
          acc2[rg][cg] = __builtin_amdgcn_mfma_f32_16x16x32_bf16(am[rg], BS[kh * 4 + cg], \
                                                                 acc2[rg][cg], 0, 0, 0); \
        }                                                                                 \
    }                                                                                     \
    __builtin_amdgcn_s_setprio(0);                                                        \
  } while (0)

#define SYNC() do { FENCE(); WAITLGKM(); FENCE(); BARRIER(); FENCE(); } while (0)

  // ---- prologue ----
  ISSUE_A(x0, x1, 0);
  LOADB(bA, 0);
  ISSUE_A(y0, y1, 1);
  XFORM(x0, x1, aBuf0, mBuf0);   // compiler auto-waits A(0) regs precisely
  SYNC();

  // ---- steady: tiles 0..125, unrolled by 2 for static reg/buffer names ----
  for (int kt = 0; kt < 126; kt += 2) {
    // even tile kt: uses aBuf0/mBuf0 + bA
    ISSUE_A(x0, x1, kt + 2);
    LOADB(bB, kt + 1);
    FENCE();                     // pin load issue before the MFMA cluster
    MFMA_TILE(aBuf0, mBuf0, bA);
    XFORM(y0, y1, aBuf1, mBuf1);
    SYNC();
    // odd tile kt+1: uses aBuf1/mBuf1 + bB
    ISSUE_A(y0, y1, kt + 3);
    LOADB(bA, kt + 2);
    FENCE();
    MFMA_TILE(aBuf1, mBuf1, bB);
    XFORM(x0, x1, aBuf0, mBuf0);
    SYNC();
  }

  // ---- tail: tile 126 ----
  LOADB(bB, 127);
  FENCE();
  MFMA_TILE(aBuf0, mBuf0, bA);
  XFORM(y0, y1, aBuf1, mBuf1);   // A(127)
  SYNC();
  // ---- tail: tile 127 ----
  MFMA_TILE(aBuf1, mBuf1, bB);

  // ---- stats reduction: 8 lanes per row (lanes differing in sp bits) ----
#pragma unroll
  for (int o = 1; o < 8; o <<= 1) {
    s1d += __shfl_xor(s1d, o);
    cnt += __shfl_xor(cnt, o);
  }
  __syncthreads();               // K-loop fully done -> safe to reuse aBuf0
  float* const invsS = (float*)aBuf0;   // 32 floats
  float* const rdegS = invsS + 32;      // 32 floats
  if (sp == 0) {
    double sq = sqrt((double)cnt);
    invsS[sm] = (cnt > 0) ? (float)(1.0 / sq) : 0.0f;
    rdegS[sm] = (float)(1.0 / (s1d + sq));
  }
  __syncthreads();

  // ---- epilogue: (acc1 + invs*acc2) * rdeg, store fp32 ----
#pragma unroll
  for (int rg = 0; rg < 2; ++rg) {
    int rb = rg * 16 + ((lane >> 4) << 2);
#pragma unroll
    for (int cg = 0; cg < 4; ++cg) {
      int col = bcol + wv * 64 + cg * 16 + (lane & 15);
#pragma unroll
      for (int r = 0; r < 4; ++r) {
        int rl = rb + r;
        out[(size_t)(brow + rl) * DDIM + col] =
            (acc1[rg][cg][r] + invsS[rl] * acc2[rg][cg][r]) * rdegS[rl];
      }
    }
  }
#undef ISSUE_A
#undef LOADB
#undef XFORM
#undef MFMA_TILE
#undef SYNC
}

extern "C" void kernel_launch(void* const* d_in, const int* in_sizes, int n_in,
                              void* d_out, int out_size, void* d_ws, size_t ws_size,
                              hipStream_t stream) {
  const float* cur = (const float*)d_in[0];          // [8192, 512] fp32
  const float* incm = (const float*)d_in[1];         // [8192, 8192] fp32
  float* out = (float*)d_out;                        // [8192, 512] fp32
  unsigned char* bws = (unsigned char*)d_ws;         // 8MB B chunks

  hipLaunchKernelGGL(bprep_kernel, dim3((NROWS * DDIM / 8) / 256), dim3(256), 0, stream,
                     cur, bws);
  hipLaunchKernelGGL(gemm_kernel, dim3(512), dim3(256), 0, stream, incm, bws, out);
}